// Round 7
// baseline (1543.595 us; speedup 1.0000x reference)
//
#include <hip/hip_runtime.h>
#include <hip/hip_bf16.h>

typedef __hip_bfloat16 bf16;
typedef __attribute__((ext_vector_type(4))) float f32x4;
typedef __attribute__((ext_vector_type(8))) short short8;
typedef __attribute__((ext_vector_type(4))) short short4v;

#define NEGBIG (-3.0e38f)

__device__ __forceinline__ unsigned short f2b(float x) {
  union { float f; unsigned int u; } v; v.f = x;
  unsigned int r = v.u + 0x7fffu + ((v.u >> 16) & 1u);
  return (unsigned short)(r >> 16);
}

__device__ __forceinline__ void gl16(const void* g, void* l) {
  __builtin_amdgcn_global_load_lds(
      (const __attribute__((address_space(1))) unsigned int*)g,
      (__attribute__((address_space(3))) unsigned int*)l, 16, 0, 0);
}

// bijective XCD-grouping swizzle (m204): contiguous tile range per XCD
__device__ __forceinline__ int xcd_swz(int orig, int nwg) {
  const int q = nwg >> 3, r = nwg & 7;
  const int xcd = orig & 7;
  const int base = (xcd < r) ? xcd * (q + 1) : r * (q + 1) + (xcd - r) * q;
  return base + (orig >> 3);
}

// ---------------- weight f32 -> bf16 (row-major) ----------------
__global__ __launch_bounds__(256) void cvt_w_kernel(
    const float* __restrict__ a, const float* __restrict__ b,
    const float* __restrict__ c, const float* __restrict__ d,
    bf16* __restrict__ dst) {
  const int t = blockIdx.x * 256 + threadIdx.x;
  const float* srcs[4] = {a, b, c, d};
#pragma unroll
  for (int w = 0; w < 4; ++w) {
    const f32x4 v = *(const f32x4*)(srcs[w] + (size_t)t * 4);
    short4v o;
    o[0] = (short)f2b(v[0]); o[1] = (short)f2b(v[1]);
    o[2] = (short)f2b(v[2]); o[3] = (short)f2b(v[3]);
    *(short4v*)((short*)dst + (size_t)w * 262144 + (size_t)t * 4) = o;
  }
}

// ---- bias table -> per-(head, frag-element) layout, pads = NEGBIG ----
__global__ __launch_bounds__(256) void prep_rpbL(const float* __restrict__ btab,
                                                 float* __restrict__ rpbL) {
  const int g = blockIdx.x * 256 + threadIdx.x;
  const int lane = g & 63, mn = (g >> 6) & 15, h = g >> 10;
  const int m = mn >> 2, n = mn & 3, l15 = lane & 15, lg = lane >> 4;
  const int cc = n * 16 + l15;
  const int aj = cc / 7, bj = cc % 7;
  f32x4 o;
#pragma unroll
  for (int reg = 0; reg < 4; ++reg) {
    const int i = m * 16 + lg * 4 + reg;
    if (i < 49 && cc < 49) {
      const int t = (i / 7 - aj + 6) * 13 + (i % 7 - bj + 6);
      o[reg] = btab[t * 16 + h];
    } else {
      o[reg] = NEGBIG;
    }
  }
  ((f32x4*)rpbL)[g] = o;
}

// ---- mask -> per-(window, frag-element) layout, pads = 0 ----
__global__ __launch_bounds__(256) void prep_maskL(const float* __restrict__ mask,
                                                  float* __restrict__ maskL) {
  const int g = blockIdx.x * 256 + threadIdx.x;
  const int lane = g & 63, mn = (g >> 6) & 15, wm = g >> 10;
  const int m = mn >> 2, n = mn & 3, l15 = lane & 15, lg = lane >> 4;
  const int cc = n * 16 + l15;
  f32x4 o;
#pragma unroll
  for (int reg = 0; reg < 4; ++reg) {
    const int i = m * 16 + lg * 4 + reg;
    o[reg] = (i < 49 && cc < 49) ? mask[(size_t)wm * 2401 + i * 49 + cc] : 0.f;
  }
  ((f32x4*)maskL)[g] = o;
}

// ---------------- fused KQV GEMM, ring-3, A reg-staged from f32 -------------
// grid 12*gy, XCD-swizzled; bn%12: cls = bn>>2 (0=K,1=Q,2=V^T), bnl = bn&3.
// 128x128 tile, BK=32, 4 waves. LDS 3 x (A 8KB + B 8KB) = 48KB -> 3 blocks/CU.
// Per iter: issue A-f32 loads + B gl16 for tile t+2; ds_read+MFMA tile t;
// cvt+ds_write A(t+2); end wait = vmcnt(2) lgkmcnt(0) (B(t+2) stays in flight).
__global__ __launch_bounds__(256, 3) void gemm_kqv(
    const float* __restrict__ Alf, const float* __restrict__ Agf,
    const short* __restrict__ wbf, const float* __restrict__ bk,
    const float* __restrict__ bq, const float* __restrict__ bv, float qscale,
    bf16* __restrict__ k_ws, bf16* __restrict__ q_ws, bf16* __restrict__ vT_ws,
    int M) {
  __shared__ char lds[49152];
  const int nwg = gridDim.x;
  const int t0 = xcd_swz(blockIdx.x, nwg);
  const int bn = t0 % 12, bm = t0 / 12;
  const int cls = bn >> 2, bnl = bn & 3;
  const int tid = threadIdx.x, lane = tid & 63, wid = tid >> 6;
  const int wr = wid >> 1, wc = wid & 1, l15 = lane & 15, lg = lane >> 4;
  const float* Af = (cls == 1) ? Agf : Alf;
  const char* Bb = (const char*)(wbf + (size_t)cls * 262144);
  const bool swap = (cls == 2);

  // staging geometry: 512 slots of 16B = 128 rows x 4 slot-cols (64 bf16 k)
  const int gS0 = tid, gS1 = tid + 256;
  const int rowS0 = gS0 >> 2, rowS1 = gS1 >> 2;
  const int c4S0 = (gS0 & 3) ^ ((rowS0 >> 1) & 3);
  const int c4S1 = (gS1 & 3) ^ ((rowS1 >> 1) & 3);
  const int gr0 = bm * 128 + rowS0, gr1 = bm * 128 + rowS1;
  const bool v0 = gr0 < M, v1 = gr1 < M;
  const float* ap0 = Af + (size_t)gr0 * 512 + c4S0 * 8;
  const float* ap1 = Af + (size_t)gr1 * 512 + c4S1 * 8;
  const char* bp0 = Bb + (size_t)(bnl * 128 + rowS0) * 1024 + c4S0 * 16;
  const char* bp1 = Bb + (size_t)(bnl * 128 + rowS1) * 1024 + c4S1 * 16;

  f32x4 a00 = (f32x4){0.f, 0.f, 0.f, 0.f}, a01 = a00, a10 = a00, a11 = a00;

#define ISSUE_A(k0)                                                       \
  do {                                                                    \
    if (v0) {                                                             \
      a00 = *(const f32x4*)(ap0 + (k0));                                  \
      a01 = *(const f32x4*)(ap0 + (k0) + 4);                              \
    }                                                                     \
    if (v1) {                                                             \
      a10 = *(const f32x4*)(ap1 + (k0));                                  \
      a11 = *(const f32x4*)(ap1 + (k0) + 4);                              \
    }                                                                     \
  } while (0)
#define ISSUE_B(buf, k0)                                                  \
  do {                                                                    \
    gl16(bp0 + (size_t)(k0) * 2, (buf) + 8192 + gS0 * 16);                \
    gl16(bp1 + (size_t)(k0) * 2, (buf) + 8192 + gS1 * 16);                \
  } while (0)
#define WRITE_A(buf)                                                      \
  do {                                                                    \
    if (v0) {                                                             \
      short8 u;                                                           \
      u[0] = (short)f2b(a00[0]); u[1] = (short)f2b(a00[1]);               \
      u[2] = (short)f2b(a00[2]); u[3] = (short)f2b(a00[3]);               \
      u[4] = (short)f2b(a01[0]); u[5] = (short)f2b(a01[1]);               \
      u[6] = (short)f2b(a01[2]); u[7] = (short)f2b(a01[3]);               \
      *(short8*)((buf) + gS0 * 16) = u;                                   \
    }                                                                     \
    if (v1) {                                                             \
      short8 u;                                                           \
      u[0] = (short)f2b(a10[0]); u[1] = (short)f2b(a10[1]);               \
      u[2] = (short)f2b(a10[2]); u[3] = (short)f2b(a10[3]);               \
      u[4] = (short)f2b(a11[0]); u[5] = (short)f2b(a11[1]);               \
      u[6] = (short)f2b(a11[2]); u[7] = (short)f2b(a11[3]);               \
      *(short8*)((buf) + gS1 * 16) = u;                                   \
    }                                                                     \
  } while (0)

  f32x4 acc[4][4];
#pragma unroll
  for (int m = 0; m < 4; ++m)
#pragma unroll
    for (int n = 0; n < 4; ++n) acc[m][n] = (f32x4){0.f, 0.f, 0.f, 0.f};

  // prologue: tiles 0,1 (A-issue before B so reg-wait leaves B in flight)
  ISSUE_A(0); ISSUE_B(lds, 0); WRITE_A(lds);
  ISSUE_A(32); ISSUE_B(lds + 16384, 32); WRITE_A(lds + 16384);
  asm volatile("s_waitcnt vmcnt(2) lgkmcnt(0)" ::: "memory");
  __builtin_amdgcn_s_barrier();
  __builtin_amdgcn_sched_barrier(0);

#pragma unroll 1
  for (int t = 0; t < 16; ++t) {
    char* cbuf = lds + (t % 3) * 16384;
    char* sbuf = lds + ((t + 2) % 3) * 16384;
    if (t < 14) { ISSUE_A((t + 2) * 32); ISSUE_B(sbuf, (t + 2) * 32); }
    const char* fa = swap ? cbuf + 8192 : cbuf;
    const char* fb = swap ? cbuf : cbuf + 8192;
    short8 af[4], bfr[4];
#pragma unroll
    for (int m = 0; m < 4; ++m) {
      const int r = wr * 64 + m * 16 + l15;
      af[m] = *(const short8*)(fa + r * 64 + ((lg ^ ((r >> 1) & 3)) << 4));
    }
#pragma unroll
    for (int n = 0; n < 4; ++n) {
      const int r = wc * 64 + n * 16 + l15;
      bfr[n] = *(const short8*)(fb + r * 64 + ((lg ^ ((r >> 1) & 3)) << 4));
    }
    __builtin_amdgcn_s_setprio(1);
#pragma unroll
    for (int m = 0; m < 4; ++m)
#pragma unroll
      for (int n = 0; n < 4; ++n)
        acc[m][n] = __builtin_amdgcn_mfma_f32_16x16x32_bf16(
            af[m], bfr[n], acc[m][n], 0, 0, 0);
    __builtin_amdgcn_s_setprio(0);
    if (t < 14) WRITE_A(sbuf);
    if (t < 14) {
      asm volatile("s_waitcnt vmcnt(2) lgkmcnt(0)" ::: "memory");
    } else if (t == 14) {
      asm volatile("s_waitcnt vmcnt(0) lgkmcnt(0)" ::: "memory");
    }
    if (t < 15) {
      __builtin_amdgcn_s_barrier();
      __builtin_amdgcn_sched_barrier(0);
    }
  }
#undef ISSUE_A
#undef ISSUE_B
#undef WRITE_A

  if (cls == 2) {  // V^T epilogue: rows=channels, cols=tokens
#pragma unroll
    for (int m = 0; m < 4; ++m) {
#pragma unroll
      for (int n = 0; n < 4; ++n) {
        const int tok = bm * 128 + wc * 64 + n * 16 + l15;
        if (tok < M) {
          const int w = tok / 49, nt = tok - w * 49;
#pragma unroll
          for (int reg = 0; reg < 4; ++reg) {
            const int ch = bnl * 128 + wr * 64 + m * 16 + lg * 4 + reg;
            const float v = acc[m][n][reg] + bv[ch];
            const int hh = ch >> 5, dd = ch & 31;
            vT_ws[(((size_t)w * 16 + hh) * 32 + dd) * 64 + nt] =
                __float2bfloat16(v);
          }
        }
      }
    }
  } else {
    const float* bb = (cls == 0) ? bk : bq;
    bf16* dp = (cls == 0) ? k_ws : q_ws;
    const float sc = (cls == 0) ? 1.0f : qscale;
#pragma unroll
    for (int m = 0; m < 4; ++m) {
#pragma unroll
      for (int n = 0; n < 4; ++n) {
        const int c = bnl * 128 + wc * 64 + n * 16 + l15;
        const float bvv = bb[c];
        const int hh = c >> 5, dd = c & 31;
#pragma unroll
        for (int reg = 0; reg < 4; ++reg) {
          const int r = bm * 128 + wr * 64 + m * 16 + lg * 4 + reg;
          if (r < M) {
            const int w = r / 49, nt = r - w * 49;
            dp[(((size_t)w * 16 + hh) * 49 + nt) * 32 + dd] =
                __float2bfloat16((acc[m][n][reg] + bvv) * sc);
          }
        }
      }
    }
  }
}

// ---------------- proj GEMM: ring-3, all-gl16, f32 out [r][512] -------------
__global__ __launch_bounds__(256, 3) void gemm_p(const short* __restrict__ Abf,
                                                 const short* __restrict__ Bbf,
                                                 const float* __restrict__ bias,
                                                 float* __restrict__ dst,
                                                 int M) {
  __shared__ char lds[49152];
  const int nwg = gridDim.x;
  const int t0 = xcd_swz(blockIdx.x, nwg);
  const int bn = t0 & 3, bm = t0 >> 2;
  const int tid = threadIdx.x, lane = tid & 63, wid = tid >> 6;
  const int wr = wid >> 1, wc = wid & 1, l15 = lane & 15, lg = lane >> 4;

  const int gS0 = tid, gS1 = tid + 256;
  const int rowS0 = gS0 >> 2, rowS1 = gS1 >> 2;
  const int c4S0 = (gS0 & 3) ^ ((rowS0 >> 1) & 3);
  const int c4S1 = (gS1 & 3) ^ ((rowS1 >> 1) & 3);
  const char* Ab = (const char*)Abf;
  const char* Bb = (const char*)Bbf;
  // A rows may exceed M in last tile: gl16 overruns into q_ws region (benign)
  const char* ap0 = Ab + (size_t)(bm * 128 + rowS0) * 1024 + c4S0 * 16;
  const char* ap1 = Ab + (size_t)(bm * 128 + rowS1) * 1024 + c4S1 * 16;
  const char* bp0 = Bb + (size_t)(bn * 128 + rowS0) * 1024 + c4S0 * 16;
  const char* bp1 = Bb + (size_t)(bn * 128 + rowS1) * 1024 + c4S1 * 16;

#define STAGE_P(buf, k0)                                                  \
  do {                                                                    \
    gl16(ap0 + (size_t)(k0) * 2, (buf) + gS0 * 16);                       \
    gl16(ap1 + (size_t)(k0) * 2, (buf) + gS1 * 16);                       \
    gl16(bp0 + (size_t)(k0) * 2, (buf) + 8192 + gS0 * 16);                \
    gl16(bp1 + (size_t)(k0) * 2, (buf) + 8192 + gS1 * 16);                \
  } while (0)

  f32x4 acc[4][4];
#pragma unroll
  for (int m = 0; m < 4; ++m)
#pragma unroll
    for (int n = 0; n < 4; ++n) acc[m][n] = (f32x4){0.f, 0.f, 0.f, 0.f};

  STAGE_P(lds, 0);
  STAGE_P(lds + 16384, 32);
  asm volatile("s_waitcnt vmcnt(4)" ::: "memory");
  __builtin_amdgcn_s_barrier();
  __builtin_amdgcn_sched_barrier(0);

#pragma unroll 1
  for (int t = 0; t < 16; ++t) {
    char* cbuf = lds + (t % 3) * 16384;
    char* sbuf = lds + ((t + 2) % 3) * 16384;
    if (t < 14) STAGE_P(sbuf, (t + 2) * 32);
    short8 af[4], bfr[4];
#pragma unroll
    for (int m = 0; m < 4; ++m) {
      const int r = wr * 64 + m * 16 + l15;
      af[m] = *(const short8*)(cbuf + r * 64 + ((lg ^ ((r >> 1) & 3)) << 4));
    }
#pragma unroll
    for (int n = 0; n < 4; ++n) {
      const int r = wc * 64 + n * 16 + l15;
      bfr[n] =
          *(const short8*)(cbuf + 8192 + r * 64 + ((lg ^ ((r >> 1) & 3)) << 4));
    }
    __builtin_amdgcn_s_setprio(1);
#pragma unroll
    for (int m = 0; m < 4; ++m)
#pragma unroll
      for (int n = 0; n < 4; ++n)
        acc[m][n] = __builtin_amdgcn_mfma_f32_16x16x32_bf16(
            af[m], bfr[n], acc[m][n], 0, 0, 0);
    __builtin_amdgcn_s_setprio(0);
    if (t < 14) {
      asm volatile("s_waitcnt vmcnt(4)" ::: "memory");
    } else if (t == 14) {
      asm volatile("s_waitcnt vmcnt(0)" ::: "memory");
    }
    if (t < 15) {
      __builtin_amdgcn_s_barrier();
      __builtin_amdgcn_sched_barrier(0);
    }
  }
#undef STAGE_P

#pragma unroll
  for (int m = 0; m < 4; ++m) {
#pragma unroll
    for (int n = 0; n < 4; ++n) {
      const int c = bn * 128 + wc * 64 + n * 16 + l15;
      const float bvv = bias[c];
#pragma unroll
      for (int reg = 0; reg < 4; ++reg) {
        const int r = bm * 128 + wr * 64 + m * 16 + lg * 4 + reg;
        if (r < M) dst[(size_t)r * 512 + c] = acc[m][n][reg] + bvv;
      }
    }
  }
}

// ---------------- windowed attention: 1 head per wave, no barriers ---------
__global__ __launch_bounds__(256) void attn_win2(
    const bf16* __restrict__ q_ws, const bf16* __restrict__ k_ws,
    const bf16* __restrict__ vT_ws, const float* __restrict__ rpbL,
    const float* __restrict__ maskL, bf16* __restrict__ x_ws, int wstart) {
  __shared__ short sP[4][4096];
  const int tid = threadIdx.x, lane = tid & 63, wid = tid >> 6;
  const int l15 = lane & 15, lg = lane >> 4;
  const int wl = blockIdx.x;
  const int h = blockIdx.y * 4 + wid;
  const int wg = wstart + wl;
  char* Pl = (char*)sP[wid];
  const size_t base = ((size_t)wl * 16 + h) * 1568;
  const short8 z8 = (short8){0, 0, 0, 0, 0, 0, 0, 0};

  short8 qf[4], kf[4];
#pragma unroll
  for (int m = 0; m < 4; ++m) {
    const int r = m * 16 + l15;
    qf[m] = (r < 49) ? *(const short8*)(q_ws + base + r * 32 + lg * 8) : z8;
    kf[m] = (r < 49) ? *(const short8*)(k_ws + base + r * 32 + lg * 8) : z8;
  }
  f32x4 lc[4][4];
#pragma unroll
  for (int m = 0; m < 4; ++m)
#pragma unroll
    for (int n = 0; n < 4; ++n)
      lc[m][n] = __builtin_amdgcn_mfma_f32_16x16x32_bf16(
          qf[m], kf[n], (f32x4){0.f, 0.f, 0.f, 0.f}, 0, 0, 0);

  const f32x4* rbp = (const f32x4*)rpbL + (size_t)h * 1024 + lane;
  const f32x4* mkp = (const f32x4*)maskL + (size_t)(wg & 1023) * 1024 + lane;
#pragma unroll
  for (int m = 0; m < 4; ++m)
#pragma unroll
    for (int n = 0; n < 4; ++n) {
      const int mn = m * 4 + n;
      lc[m][n] += rbp[mn * 64] + mkp[mn * 64];
    }

#pragma unroll
  for (int m = 0; m < 4; ++m) {
#pragma unroll
    for (int reg = 0; reg < 4; ++reg) {
      float vmax = fmaxf(fmaxf(lc[m][0][reg], lc[m][1][reg]),
                         fmaxf(lc[m][2][reg], lc[m][3][reg]));
#pragma unroll
      for (int off = 1; off < 16; off <<= 1)
        vmax = fmaxf(vmax, __shfl_xor(vmax, off, 64));
      float e[4], ssum = 0.f;
#pragma unroll
      for (int n = 0; n < 4; ++n) {
        e[n] = __expf(lc[m][n][reg] - vmax);
        ssum += e[n];
      }
#pragma unroll
      for (int off = 1; off < 16; off <<= 1) ssum += __shfl_xor(ssum, off, 64);
      const float inv = __builtin_amdgcn_rcpf(ssum);
      const int i = m * 16 + lg * 4 + reg;
#pragma unroll
      for (int n = 0; n < 4; ++n) {
        const int cc = n * 16 + l15;
        *(unsigned short*)(Pl + i * 128 + ((2 * cc) ^ ((i & 7) << 4))) =
            f2b(e[n] * inv);
      }
    }
  }

  f32x4 xacc[4][2];
#pragma unroll
  for (int m = 0; m < 4; ++m)
#pragma unroll
    for (int n = 0; n < 2; ++n) xacc[m][n] = (f32x4){0.f, 0.f, 0.f, 0.f};
  const size_t vbase = ((size_t)wl * 16 + h) * 2048;
#pragma unroll
  for (int s = 0; s < 2; ++s) {
    short8 pf[4], vf[2];
#pragma unroll
    for (int m = 0; m < 4; ++m) {
      const int i = m * 16 + l15;
      pf[m] = *(const short8*)(Pl + i * 128 +
                               ((s * 64 + lg * 16) ^ ((i & 7) << 4)));
    }
#pragma unroll
    for (int n = 0; n < 2; ++n) {
      const int dd = n * 16 + l15;
      short8 vv = *(const short8*)(vT_ws + vbase + dd * 64 + s * 32 + lg * 8);
      if (s == 1) {
        if (lg == 3) vv = z8;
        else if (lg == 2) {
          vv[1] = 0; vv[2] = 0; vv[3] = 0; vv[4] = 0;
          vv[5] = 0; vv[6] = 0; vv[7] = 0;
        }
      }
      vf[n] = vv;
    }
#pragma unroll
    for (int m = 0; m < 4; ++m)
#pragma unroll
      for (int n = 0; n < 2; ++n)
        xacc[m][n] = __builtin_amdgcn_mfma_f32_16x16x32_bf16(
            pf[m], vf[n], xacc[m][n], 0, 0, 0);
  }

#pragma unroll
  for (int m = 0; m < 4; ++m)
#pragma unroll
    for (int n = 0; n < 2; ++n)
#pragma unroll
      for (int reg = 0; reg < 4; ++reg) {
        const int i = m * 16 + lg * 4 + reg;
        const int dd = n * 16 + l15;
        *(unsigned short*)(Pl + i * 80 + ((2 * dd) ^ ((i & 3) << 4))) =
            f2b(xacc[m][n][reg]);
      }
#pragma unroll
  for (int g = 0; g < 4; ++g) {
    const int row = g * 16 + (lane >> 2);
    if (row < 49) {
      const short8 xv = *(const short8*)(
          Pl + row * 80 + (((lane & 3) * 16) ^ ((row & 3) << 4)));
      *(short8*)(x_ws + ((size_t)wl * 49 + row) * 512 + h * 32 +
                 (lane & 3) * 8) = xv;
    }
  }
}

extern "C" void kernel_launch(void* const* d_in, const int* in_sizes, int n_in,
                              void* d_out, int out_size, void* d_ws,
                              size_t ws_size, hipStream_t stream) {
  const float* lf   = (const float*)d_in[0];
  const float* gfx  = (const float*)d_in[1];
  const float* mask = (const float*)d_in[2];
  const float* btab = (const float*)d_in[3];
  const float* Wk = (const float*)d_in[4];  const float* bk = (const float*)d_in[5];
  const float* Wq = (const float*)d_in[6];  const float* bq = (const float*)d_in[7];
  const float* Wv = (const float*)d_in[8];  const float* bv = (const float*)d_in[9];
  const float* Wp = (const float*)d_in[10]; const float* bp = (const float*)d_in[11];
  float* out = (float*)d_out;

  char* ws = (char*)d_ws;
  short* wbf = (short*)ws;  // 4 x 512x512 bf16 = 2 MB
  size_t off = (size_t)4 * 262144 * 2;
  float* rpbL = (float*)(ws + off); off += (size_t)16 * 4096 * 4;     // 256 KB
  float* maskL = (float*)(ws + off); off += (size_t)1024 * 4096 * 4;  // 16 MB

  const size_t perw = 3 * 50176 + 65536;  // x,q,k + vT = 216064 B/window
  size_t avail = (ws_size > off + 65536) ? ws_size - off - 65536 : 0;
  int CH = (int)(avail / perw);
  if (CH > 4096) CH = 4096;
  if (CH < 1) CH = 1;

  bf16* x_ws = (bf16*)(ws + off); off += (size_t)CH * 50176;
  bf16* q_ws = (bf16*)(ws + off); off += (size_t)CH * 50176;
  bf16* k_ws = (bf16*)(ws + off); off += (size_t)CH * 50176;
  bf16* vT_ws = (bf16*)(ws + off); off += (size_t)CH * 65536;

  cvt_w_kernel<<<256, 256, 0, stream>>>(Wk, Wq, Wv, Wp, (bf16*)wbf);
  prep_rpbL<<<64, 256, 0, stream>>>(btab, rpbL);
  prep_maskL<<<4096, 256, 0, stream>>>(mask, maskL);

  const float qscale = 0.17677669529663687f;  // 1/sqrt(32)
  for (int wstart = 0; wstart < 4096; wstart += CH) {
    const int nwin = (4096 - wstart < CH) ? (4096 - wstart) : CH;
    const int M = nwin * 49;
    const int gy = (M + 127) / 128;
    gemm_kqv<<<12 * gy, 256, 0, stream>>>(lf + (size_t)wstart * 25088,
                                          gfx + (size_t)wstart * 25088, wbf,
                                          bk, bq, bv, qscale, k_ws, q_ws,
                                          vT_ws, M);
    attn_win2<<<dim3(nwin, 4), 256, 0, stream>>>(q_ws, k_ws, vT_ws, rpbL,
                                                 maskL, x_ws, wstart);
    gemm_p<<<4 * gy, 256, 0, stream>>>((const short*)x_ws, wbf + 3 * 262144,
                                       bp, out + (size_t)wstart * 25088, M);
  }
}

// Round 8
// 1270.759 us; speedup vs baseline: 1.2147x; 1.2147x over previous
//
#include <hip/hip_runtime.h>
#include <hip/hip_bf16.h>

typedef __hip_bfloat16 bf16;
typedef __attribute__((ext_vector_type(4))) float f32x4;
typedef __attribute__((ext_vector_type(8))) short short8;
typedef __attribute__((ext_vector_type(4))) short short4v;

#define NEGBIG (-3.0e38f)

__device__ __forceinline__ unsigned short f2b(float x) {
  union { float f; unsigned int u; } v; v.f = x;
  unsigned int r = v.u + 0x7fffu + ((v.u >> 16) & 1u);
  return (unsigned short)(r >> 16);
}

__device__ __forceinline__ void gl16(const void* g, void* l) {
  __builtin_amdgcn_global_load_lds(
      (const __attribute__((address_space(1))) unsigned int*)g,
      (__attribute__((address_space(3))) unsigned int*)l, 16, 0, 0);
}

// bijective XCD-grouping swizzle (m204): contiguous tile range per XCD
__device__ __forceinline__ int xcd_swz(int orig, int nwg) {
  const int q = nwg >> 3, r = nwg & 7;
  const int xcd = orig & 7;
  const int base = (xcd < r) ? xcd * (q + 1) : r * (q + 1) + (xcd - r) * q;
  return base + (orig >> 3);
}

// ---------------- weight f32 -> bf16 (row-major) ----------------
__global__ __launch_bounds__(256) void cvt_w_kernel(
    const float* __restrict__ a, const float* __restrict__ b,
    const float* __restrict__ c, const float* __restrict__ d,
    bf16* __restrict__ dst) {
  const int t = blockIdx.x * 256 + threadIdx.x;
  const float* srcs[4] = {a, b, c, d};
#pragma unroll
  for (int w = 0; w < 4; ++w) {
    const f32x4 v = *(const f32x4*)(srcs[w] + (size_t)t * 4);
    short4v o;
    o[0] = (short)f2b(v[0]); o[1] = (short)f2b(v[1]);
    o[2] = (short)f2b(v[2]); o[3] = (short)f2b(v[3]);
    *(short4v*)((short*)dst + (size_t)w * 262144 + (size_t)t * 4) = o;
  }
}

// ---------------- activation f32 -> bf16 (row-major [M][512]) -------------
__global__ __launch_bounds__(256) void cvt_a(const float* __restrict__ src,
                                             short* __restrict__ dst, int M) {
  const int g = blockIdx.x * 256 + threadIdx.x;
  const int row = g >> 6, k8 = g & 63;
  if (row >= M) return;
  const float* sp = src + (size_t)row * 512 + k8 * 8;
  const f32x4 lo = *(const f32x4*)sp;
  const f32x4 hi = *(const f32x4*)(sp + 4);
  short8 u;
  u[0] = (short)f2b(lo[0]); u[1] = (short)f2b(lo[1]);
  u[2] = (short)f2b(lo[2]); u[3] = (short)f2b(lo[3]);
  u[4] = (short)f2b(hi[0]); u[5] = (short)f2b(hi[1]);
  u[6] = (short)f2b(hi[2]); u[7] = (short)f2b(hi[3]);
  *(short8*)(dst + (size_t)row * 512 + k8 * 8) = u;
}

// ---- bias table -> per-(head, frag-element) layout, pads = NEGBIG ----
__global__ __launch_bounds__(256) void prep_rpbL(const float* __restrict__ btab,
                                                 float* __restrict__ rpbL) {
  const int g = blockIdx.x * 256 + threadIdx.x;
  const int lane = g & 63, mn = (g >> 6) & 15, h = g >> 10;
  const int m = mn >> 2, n = mn & 3, l15 = lane & 15, lg = lane >> 4;
  const int cc = n * 16 + l15;
  const int aj = cc / 7, bj = cc % 7;
  f32x4 o;
#pragma unroll
  for (int reg = 0; reg < 4; ++reg) {
    const int i = m * 16 + lg * 4 + reg;
    if (i < 49 && cc < 49) {
      const int t = (i / 7 - aj + 6) * 13 + (i % 7 - bj + 6);
      o[reg] = btab[t * 16 + h];
    } else {
      o[reg] = NEGBIG;
    }
  }
  ((f32x4*)rpbL)[g] = o;
}

// ---- mask -> per-(window, frag-element) layout, pads = 0 ----
__global__ __launch_bounds__(256) void prep_maskL(const float* __restrict__ mask,
                                                  float* __restrict__ maskL) {
  const int g = blockIdx.x * 256 + threadIdx.x;
  const int lane = g & 63, mn = (g >> 6) & 15, wm = g >> 10;
  const int m = mn >> 2, n = mn & 3, l15 = lane & 15, lg = lane >> 4;
  const int cc = n * 16 + l15;
  f32x4 o;
#pragma unroll
  for (int reg = 0; reg < 4; ++reg) {
    const int i = m * 16 + lg * 4 + reg;
    o[reg] = (i < 49 && cc < 49) ? mask[(size_t)wm * 2401 + i * 49 + cc] : 0.f;
  }
  ((f32x4*)maskL)[g] = o;
}

// ------- m97-geometry staging: A 128x64 (16KB), B 256x64 (32KB), swizzled ----
// LDS dest linear (gl16 rule); global 16B-slot col c is fetched from c^(row&7)
// so the XOR'd ds_read below is conflict-free (rule #21).
__device__ __forceinline__ void stage_m97(const char* Ab, const char* Bb,
                                          char* As, char* Bs, int arow0,
                                          int brow0, int k0) {
  const int tid = threadIdx.x;  // 512 threads
#pragma unroll
  for (int i = 0; i < 2; ++i) {
    const int s = tid + 512 * i;  // A: 1024 slots of 16B
    const int row = s >> 3;
    const int sc = (s & 7) ^ (row & 7);
    gl16(Ab + (size_t)(arow0 + row) * 1024 + k0 * 2 + sc * 16, As + s * 16);
  }
#pragma unroll
  for (int i = 0; i < 4; ++i) {
    const int s = tid + 512 * i;  // B: 2048 slots of 16B
    const int row = s >> 3;
    const int sc = (s & 7) ^ (row & 7);
    gl16(Bb + (size_t)(brow0 + row) * 1024 + k0 * 2 + sc * 16, Bs + s * 16);
  }
}

// ---------------- fused KQV GEMM, m97 geometry ------------------------------
// grid 6*gy, XCD-swizzled; bn%6: cls = bn>>1 (0=K,1=Q,2=V^T), bnl = bn&1.
// BM=128 (tokens), BN=256 (channels), BK=64, 8 waves, single-buffer 48KB LDS
// -> 3 blocks/CU (24 waves). V^T via operand swap + remapped wave grid.
__global__ __launch_bounds__(512, 4) void gemm_kqv(
    const short* __restrict__ Al, const short* __restrict__ Ag,
    const short* __restrict__ wbf, const float* __restrict__ bk,
    const float* __restrict__ bq, const float* __restrict__ bv, float qscale,
    bf16* __restrict__ k_ws, bf16* __restrict__ q_ws, bf16* __restrict__ vT_ws,
    int M) {
  __shared__ char lds[49152];
  char* As = lds;           // [128][128B]
  char* Bs = lds + 16384;   // [256][128B]
  const int nwg = gridDim.x;
  const int t0 = xcd_swz(blockIdx.x, nwg);
  const int bn = t0 % 6, bm = t0 / 6;
  const int cls = bn >> 1, bnl = bn & 1;
  const int tid = threadIdx.x, lane = tid & 63, wid = tid >> 6;
  const int l15 = lane & 15, lg = lane >> 4;
  const bool swap = (cls == 2);
  // normal: wr (2) x wc (4); swap: cm (4, channels) x ct (2, tokens)
  const int wr = swap ? (wid & 3) : (wid >> 2);
  const int wc = swap ? (wid >> 2) : (wid & 3);
  const char* Ab = (const char*)((cls == 1) ? Ag : Al);
  const char* Bb = (const char*)(wbf + (size_t)cls * 262144);

  f32x4 acc[4][4];
#pragma unroll
  for (int m = 0; m < 4; ++m)
#pragma unroll
    for (int n = 0; n < 4; ++n) acc[m][n] = (f32x4){0.f, 0.f, 0.f, 0.f};

  const char* fam = swap ? Bs : As;  // A-operand source (m-axis rows)
  const char* fbm = swap ? As : Bs;  // B-operand source (n-axis rows)

  for (int kt = 0; kt < 8; ++kt) {
    stage_m97(Ab, Bb, As, Bs, bm * 128, bnl * 256, kt * 64);
    __syncthreads();
#pragma unroll
    for (int s = 0; s < 2; ++s) {
      short8 af[4], bfr[4];
#pragma unroll
      for (int m = 0; m < 4; ++m) {
        const int r = wr * 64 + m * 16 + l15;
        af[m] = *(const short8*)(fam + r * 128 +
                                 (((s * 4 + lg) ^ (r & 7)) << 4));
      }
#pragma unroll
      for (int n = 0; n < 4; ++n) {
        const int r = wc * 64 + n * 16 + l15;
        bfr[n] = *(const short8*)(fbm + r * 128 +
                                  (((s * 4 + lg) ^ (r & 7)) << 4));
      }
#pragma unroll
      for (int m = 0; m < 4; ++m)
#pragma unroll
        for (int n = 0; n < 4; ++n)
          acc[m][n] = __builtin_amdgcn_mfma_f32_16x16x32_bf16(
              af[m], bfr[n], acc[m][n], 0, 0, 0);
    }
    __syncthreads();
  }

  if (cls == 2) {  // V^T: m-axis = channels (256), n-axis = tokens (128)
#pragma unroll
    for (int m = 0; m < 4; ++m) {
#pragma unroll
      for (int n = 0; n < 4; ++n) {
        const int tok = bm * 128 + wc * 64 + n * 16 + l15;
        if (tok < M) {
          const int w = tok / 49, nt = tok - w * 49;
#pragma unroll
          for (int reg = 0; reg < 4; ++reg) {
            const int ch = bnl * 256 + wr * 64 + m * 16 + lg * 4 + reg;
            const float v = acc[m][n][reg] + bv[ch];
            const int hh = ch >> 5, dd = ch & 31;
            vT_ws[(((size_t)w * 16 + hh) * 32 + dd) * 64 + nt] =
                __float2bfloat16(v);
          }
        }
      }
    }
  } else {
    const float* bb = (cls == 0) ? bk : bq;
    bf16* dp = (cls == 0) ? k_ws : q_ws;
    const float sc = (cls == 0) ? 1.0f : qscale;
#pragma unroll
    for (int m = 0; m < 4; ++m) {
#pragma unroll
      for (int n = 0; n < 4; ++n) {
        const int c = bnl * 256 + wc * 64 + n * 16 + l15;
        const float bvv = bb[c];
        const int hh = c >> 5, dd = c & 31;
#pragma unroll
        for (int reg = 0; reg < 4; ++reg) {
          const int r = bm * 128 + wr * 64 + m * 16 + lg * 4 + reg;
          if (r < M) {
            const int w = r / 49, nt = r - w * 49;
            dp[(((size_t)w * 16 + hh) * 49 + nt) * 32 + dd] =
                __float2bfloat16((acc[m][n][reg] + bvv) * sc);
          }
        }
      }
    }
  }
}

// ---------------- proj GEMM, m97 geometry: f32 out [r][512] -----------------
__global__ __launch_bounds__(512, 4) void gemm_p(const short* __restrict__ Abf,
                                                 const short* __restrict__ Bbf,
                                                 const float* __restrict__ bias,
                                                 float* __restrict__ dst,
                                                 int M) {
  __shared__ char lds[49152];
  char* As = lds;
  char* Bs = lds + 16384;
  const int nwg = gridDim.x;
  const int t0 = xcd_swz(blockIdx.x, nwg);
  const int bnl = t0 & 1, bm = t0 >> 1;
  const int tid = threadIdx.x, lane = tid & 63, wid = tid >> 6;
  const int wr = wid >> 2, wc = wid & 3, l15 = lane & 15, lg = lane >> 4;

  f32x4 acc[4][4];
#pragma unroll
  for (int m = 0; m < 4; ++m)
#pragma unroll
    for (int n = 0; n < 4; ++n) acc[m][n] = (f32x4){0.f, 0.f, 0.f, 0.f};

  for (int kt = 0; kt < 8; ++kt) {
    stage_m97((const char*)Abf, (const char*)Bbf, As, Bs, bm * 128, bnl * 256,
              kt * 64);
    __syncthreads();
#pragma unroll
    for (int s = 0; s < 2; ++s) {
      short8 af[4], bfr[4];
#pragma unroll
      for (int m = 0; m < 4; ++m) {
        const int r = wr * 64 + m * 16 + l15;
        af[m] = *(const short8*)(As + r * 128 +
                                 (((s * 4 + lg) ^ (r & 7)) << 4));
      }
#pragma unroll
      for (int n = 0; n < 4; ++n) {
        const int r = wc * 64 + n * 16 + l15;
        bfr[n] = *(const short8*)(Bs + r * 128 +
                                  (((s * 4 + lg) ^ (r & 7)) << 4));
      }
#pragma unroll
      for (int m = 0; m < 4; ++m)
#pragma unroll
        for (int n = 0; n < 4; ++n)
          acc[m][n] = __builtin_amdgcn_mfma_f32_16x16x32_bf16(
              af[m], bfr[n], acc[m][n], 0, 0, 0);
    }
    __syncthreads();
  }

#pragma unroll
  for (int m = 0; m < 4; ++m) {
#pragma unroll
    for (int n = 0; n < 4; ++n) {
      const int c = bnl * 256 + wc * 64 + n * 16 + l15;
      const float bvv = bias[c];
#pragma unroll
      for (int reg = 0; reg < 4; ++reg) {
        const int r = bm * 128 + wr * 64 + m * 16 + lg * 4 + reg;
        if (r < M) dst[(size_t)r * 512 + c] = acc[m][n][reg] + bvv;
      }
    }
  }
}

// ---------------- windowed attention: 1 head per wave, no barriers ---------
__global__ __launch_bounds__(256) void attn_win2(
    const bf16* __restrict__ q_ws, const bf16* __restrict__ k_ws,
    const bf16* __restrict__ vT_ws, const float* __restrict__ rpbL,
    const float* __restrict__ maskL, bf16* __restrict__ x_ws, int wstart) {
  __shared__ short sP[4][4096];
  const int tid = threadIdx.x, lane = tid & 63, wid = tid >> 6;
  const int l15 = lane & 15, lg = lane >> 4;
  const int wl = blockIdx.x;
  const int h = blockIdx.y * 4 + wid;
  const int wg = wstart + wl;
  char* Pl = (char*)sP[wid];
  const size_t base = ((size_t)wl * 16 + h) * 1568;
  const short8 z8 = (short8){0, 0, 0, 0, 0, 0, 0, 0};

  short8 qf[4], kf[4];
#pragma unroll
  for (int m = 0; m < 4; ++m) {
    const int r = m * 16 + l15;
    qf[m] = (r < 49) ? *(const short8*)(q_ws + base + r * 32 + lg * 8) : z8;
    kf[m] = (r < 49) ? *(const short8*)(k_ws + base + r * 32 + lg * 8) : z8;
  }
  f32x4 lc[4][4];
#pragma unroll
  for (int m = 0; m < 4; ++m)
#pragma unroll
    for (int n = 0; n < 4; ++n)
      lc[m][n] = __builtin_amdgcn_mfma_f32_16x16x32_bf16(
          qf[m], kf[n], (f32x4){0.f, 0.f, 0.f, 0.f}, 0, 0, 0);

  const f32x4* rbp = (const f32x4*)rpbL + (size_t)h * 1024 + lane;
  const f32x4* mkp = (const f32x4*)maskL + (size_t)(wg & 1023) * 1024 + lane;
#pragma unroll
  for (int m = 0; m < 4; ++m)
#pragma unroll
    for (int n = 0; n < 4; ++n) {
      const int mn = m * 4 + n;
      lc[m][n] += rbp[mn * 64] + mkp[mn * 64];
    }

#pragma unroll
  for (int m = 0; m < 4; ++m) {
#pragma unroll
    for (int reg = 0; reg < 4; ++reg) {
      float vmax = fmaxf(fmaxf(lc[m][0][reg], lc[m][1][reg]),
                         fmaxf(lc[m][2][reg], lc[m][3][reg]));
#pragma unroll
      for (int off = 1; off < 16; off <<= 1)
        vmax = fmaxf(vmax, __shfl_xor(vmax, off, 64));
      float e[4], ssum = 0.f;
#pragma unroll
      for (int n = 0; n < 4; ++n) {
        e[n] = __expf(lc[m][n][reg] - vmax);
        ssum += e[n];
      }
#pragma unroll
      for (int off = 1; off < 16; off <<= 1) ssum += __shfl_xor(ssum, off, 64);
      const float inv = __builtin_amdgcn_rcpf(ssum);
      const int i = m * 16 + lg * 4 + reg;
#pragma unroll
      for (int n = 0; n < 4; ++n) {
        const int cc = n * 16 + l15;
        *(unsigned short*)(Pl + i * 128 + ((2 * cc) ^ ((i & 7) << 4))) =
            f2b(e[n] * inv);
      }
    }
  }

  f32x4 xacc[4][2];
#pragma unroll
  for (int m = 0; m < 4; ++m)
#pragma unroll
    for (int n = 0; n < 2; ++n) xacc[m][n] = (f32x4){0.f, 0.f, 0.f, 0.f};
  const size_t vbase = ((size_t)wl * 16 + h) * 2048;
#pragma unroll
  for (int s = 0; s < 2; ++s) {
    short8 pf[4], vf[2];
#pragma unroll
    for (int m = 0; m < 4; ++m) {
      const int i = m * 16 + l15;
      pf[m] = *(const short8*)(Pl + i * 128 +
                               ((s * 64 + lg * 16) ^ ((i & 7) << 4)));
    }
#pragma unroll
    for (int n = 0; n < 2; ++n) {
      const int dd = n * 16 + l15;
      short8 vv = *(const short8*)(vT_ws + vbase + dd * 64 + s * 32 + lg * 8);
      if (s == 1) {
        if (lg == 3) vv = z8;
        else if (lg == 2) {
          vv[1] = 0; vv[2] = 0; vv[3] = 0; vv[4] = 0;
          vv[5] = 0; vv[6] = 0; vv[7] = 0;
        }
      }
      vf[n] = vv;
    }
#pragma unroll
    for (int m = 0; m < 4; ++m)
#pragma unroll
      for (int n = 0; n < 2; ++n)
        xacc[m][n] = __builtin_amdgcn_mfma_f32_16x16x32_bf16(
            pf[m], vf[n], xacc[m][n], 0, 0, 0);
  }

#pragma unroll
  for (int m = 0; m < 4; ++m)
#pragma unroll
    for (int n = 0; n < 2; ++n)
#pragma unroll
      for (int reg = 0; reg < 4; ++reg) {
        const int i = m * 16 + lg * 4 + reg;
        const int dd = n * 16 + l15;
        *(unsigned short*)(Pl + i * 80 + ((2 * dd) ^ ((i & 3) << 4))) =
            f2b(xacc[m][n][reg]);
      }
#pragma unroll
  for (int g = 0; g < 4; ++g) {
    const int row = g * 16 + (lane >> 2);
    if (row < 49) {
      const short8 xv = *(const short8*)(
          Pl + row * 80 + (((lane & 3) * 16) ^ ((row & 3) << 4)));
      *(short8*)(x_ws + ((size_t)wl * 49 + row) * 512 + h * 32 +
                 (lane & 3) * 8) = xv;
    }
  }
}

extern "C" void kernel_launch(void* const* d_in, const int* in_sizes, int n_in,
                              void* d_out, int out_size, void* d_ws,
                              size_t ws_size, hipStream_t stream) {
  const float* lf   = (const float*)d_in[0];
  const float* gfx  = (const float*)d_in[1];
  const float* mask = (const float*)d_in[2];
  const float* btab = (const float*)d_in[3];
  const float* Wk = (const float*)d_in[4];  const float* bk = (const float*)d_in[5];
  const float* Wq = (const float*)d_in[6];  const float* bq = (const float*)d_in[7];
  const float* Wv = (const float*)d_in[8];  const float* bv = (const float*)d_in[9];
  const float* Wp = (const float*)d_in[10]; const float* bp = (const float*)d_in[11];
  float* out = (float*)d_out;

  char* ws = (char*)d_ws;
  short* wbf = (short*)ws;  // 4 x 512x512 bf16 = 2 MB
  size_t off = (size_t)4 * 262144 * 2;
  float* rpbL = (float*)(ws + off); off += (size_t)16 * 4096 * 4;     // 256 KB
  float* maskL = (float*)(ws + off); off += (size_t)1024 * 4096 * 4;  // 16 MB

  const size_t perw = 2 * 49 * 1024 + 2 * 50176 + 65536;  // 266240 B/window
  size_t avail = (ws_size > off + 65536) ? ws_size - off - 65536 : 0;
  int CH = (int)((avail > 300000) ? (avail - 262144) / perw : 1);
  if (CH > 4096) CH = 4096;
  if (CH < 1) CH = 1;
  const int RWS = ((CH * 49 + 127) / 128) * 128;

  short* Al = (short*)(ws + off); off += (size_t)RWS * 1024;
  short* Ag = (short*)(ws + off); off += (size_t)RWS * 1024;
  bf16* q_ws = (bf16*)(ws + off); off += (size_t)CH * 50176;
  bf16* k_ws = (bf16*)(ws + off); off += (size_t)CH * 50176;
  bf16* vT_ws = (bf16*)(ws + off); off += (size_t)CH * 65536;
  bf16* x_ws = (bf16*)Al;  // alias: Al dead after gemm_kqv

  cvt_w_kernel<<<256, 256, 0, stream>>>(Wk, Wq, Wv, Wp, (bf16*)wbf);
  prep_rpbL<<<64, 256, 0, stream>>>(btab, rpbL);
  prep_maskL<<<4096, 256, 0, stream>>>(mask, maskL);

  const float qscale = 0.17677669529663687f;  // 1/sqrt(32)
  for (int wstart = 0; wstart < 4096; wstart += CH) {
    const int nwin = (4096 - wstart < CH) ? (4096 - wstart) : CH;
    const int M = nwin * 49;
    const int gy = (M + 127) / 128;
    const int cg = (M * 64 + 255) / 256;
    cvt_a<<<cg, 256, 0, stream>>>(lf + (size_t)wstart * 25088, Al, M);
    cvt_a<<<cg, 256, 0, stream>>>(gfx + (size_t)wstart * 25088, Ag, M);
    gemm_kqv<<<6 * gy, 512, 0, stream>>>(Al, Ag, wbf, bk, bq, bv, qscale,
                                         k_ws, q_ws, vT_ws, M);
    attn_win2<<<dim3(nwin, 4), 256, 0, stream>>>(q_ws, k_ws, vT_ws, rpbL,
                                                 maskL, x_ws, wstart);
    gemm_p<<<2 * gy, 512, 0, stream>>>((const short*)x_ws, wbf + 3 * 262144,
                                       bp, out + (size_t)wstart * 25088, M);
  }
}